// Round 6
// baseline (268.552 us; speedup 1.0000x reference)
//
#include <hip/hip_runtime.h>

// SyntacticGCN on MI355X — fp32 in/out.
// v6r: RESUBMISSION of v6 (R4 bench failed on container acquisition — infra,
// not kernel: no compile/test/timing data returned; kernel audited for hangs:
// all loops SGPR-bounded, no OOB, graph-capture-safe API usage only).
//
// v6: aggregate-then-transform; latency attack with both knobs aligned.
//   S[n, t*128+d] = sum_{e:tgt=n,t_e=t} g_e * x[src_e, d]   (gather from 25.6MB xb)
//   out[n] = relu(inp[n] + S[n,:] @ Wcat)                    (one K=512 GEMM)
//
// v6 changes (post-mortem: v2 (64-tile, 16 waves/CU) = 80.5us was fastest; v3
// raised occupancy but halved tile (2x wcatT reload + block overhead) — the
// occupancy lever was never cleanly tested):
//   - fused: 64-row tile @ 1024 thr, bounds(1024,8) -> 2 blocks/CU x 16 waves
//     = 32 waves/CU (100%) AND big tile (1563 blocks, half the wcatT traffic).
//   - cross-row pe prefetch: all 4 rows' (start,cnt) loaded upfront; row p+1's
//     pe chunk issued before row p's consume loop -> pe latency hidden, per-row
//     serial depth ~1 memory latency (was 2).
//   - pe payload = int2 (src|t, gate) 8B/edge; rel in side array written only
//     when biases nonzero (scatter reads bnz, computed in the prior dispatch).
//
// Pipeline (6 dispatches): memset | conv_hist_k | scan_block_k | scan_add_k |
//   scatter_payload_k | fused_agg_gemm_k.

typedef __attribute__((ext_vector_type(8))) short short8;
typedef __attribute__((ext_vector_type(4))) float floatx4;

#define DIM 128

static __device__ __forceinline__ float bf2f(unsigned int u16bits) {
    unsigned int x = u16bits << 16;
    return __builtin_bit_cast(float, x);
}
static __device__ __forceinline__ unsigned int f2bf(float f) {
    unsigned int x = __builtin_bit_cast(unsigned int, f);
    return (x + 0x7fffu + ((x >> 16) & 1u)) >> 16;
}

// ------- fused: conv+gate (node blocks) | hist | zcheck | weight-convert ---------
__global__ __launch_bounds__(256) void conv_hist_k(
    const float* __restrict__ inp,
    const float* __restrict__ gin,  const float* __restrict__ gout,
    const float* __restrict__ gself, const float* __restrict__ gnorel,
    const float* __restrict__ Vin, const float* __restrict__ Vout,
    const float* __restrict__ Wself, const float* __restrict__ Wnorel,
    unsigned short* __restrict__ xb, float* __restrict__ xg,
    unsigned short* __restrict__ wcatT,
    const int* __restrict__ ei, int* __restrict__ counts,
    const float* __restrict__ b_in, const float* __restrict__ b_out,
    int* __restrict__ bnz, long long nbe,
    int N, int E, int nb_conv, int nb_edge)
{
    int bx = (int)blockIdx.x;
    if (bx >= nb_conv + nb_edge + 256) {
        // weight convert: wcatT[c][k] = bf16(W_t[d][c]), k = t*128+d. 128 blocks.
        int gid = (bx - nb_conv - nb_edge - 256) * 256 + threadIdx.x; // 32768
        int k = gid >> 6;            // 0..511
        int c2 = (gid & 63) * 2;     // 0,2,..,126
        int t = k >> 7, d = k & 127;
        const float* Wt = (t == 0) ? Vin : (t == 1) ? Vout : (t == 2) ? Wself : Wnorel;
        float2 w = *(const float2*)(Wt + (size_t)d * DIM + c2);
        wcatT[(size_t)c2 * 512 + k]       = (unsigned short)f2bf(w.x);
        wcatT[(size_t)(c2 + 1) * 512 + k] = (unsigned short)f2bf(w.y);
        return;
    }
    if (bx >= nb_conv + nb_edge) {
        // sampler: 256 blocks x 256 threads, strided over the bias tables
        long long tid = (long long)(bx - nb_conv - nb_edge) * 256 + threadIdx.x;
        long long stride = nbe / 65536;
        long long i = tid * stride;
        if (i < nbe && (b_in[i] != 0.f || b_out[i] != 0.f)) *bnz = 1;
        return;
    }
    if (bx >= nb_conv) {
        int e = (bx - nb_conv) * 256 + threadIdx.x;
        if (e < E) atomicAdd(&counts[ei[E + e]], 1);
        return;
    }
    // node-conv: 4 waves x 16 nodes = 64 nodes per block.
    // Lane (q, l15): node = l15, covers k = kt*32 + q*8 .. +8 for kt=0..3.
    int wv   = threadIdx.x >> 6;
    int lane = threadIdx.x & 63;
    int q = lane >> 4, l15 = lane & 15;
    int n = bx * 64 + wv * 16 + l15;
    int rowc = n < N ? n : N - 1;
    const float* xr = inp + (size_t)rowc * DIM;

    float4 acc = make_float4(0.f, 0.f, 0.f, 0.f);
    unsigned xpk[16];
#pragma unroll
    for (int kt = 0; kt < 4; ++kt) {
        int ko = kt * 32 + q * 8;
        float4 xa = *(const float4*)(xr + ko);
        float4 xc = *(const float4*)(xr + ko + 4);
        float4 ga, gb;
        ga = *(const float4*)(gin + ko);    gb = *(const float4*)(gin + ko + 4);
        acc.x += xa.x*ga.x + xa.y*ga.y + xa.z*ga.z + xa.w*ga.w
               + xc.x*gb.x + xc.y*gb.y + xc.z*gb.z + xc.w*gb.w;
        ga = *(const float4*)(gout + ko);   gb = *(const float4*)(gout + ko + 4);
        acc.y += xa.x*ga.x + xa.y*ga.y + xa.z*ga.z + xa.w*ga.w
               + xc.x*gb.x + xc.y*gb.y + xc.z*gb.z + xc.w*gb.w;
        ga = *(const float4*)(gself + ko);  gb = *(const float4*)(gself + ko + 4);
        acc.z += xa.x*ga.x + xa.y*ga.y + xa.z*ga.z + xa.w*ga.w
               + xc.x*gb.x + xc.y*gb.y + xc.z*gb.z + xc.w*gb.w;
        ga = *(const float4*)(gnorel + ko); gb = *(const float4*)(gnorel + ko + 4);
        acc.w += xa.x*ga.x + xa.y*ga.y + xa.z*ga.z + xa.w*ga.w
               + xc.x*gb.x + xc.y*gb.y + xc.z*gb.z + xc.w*gb.w;
        xpk[kt*4+0] = f2bf(xa.x) | (f2bf(xa.y) << 16);
        xpk[kt*4+1] = f2bf(xa.z) | (f2bf(xa.w) << 16);
        xpk[kt*4+2] = f2bf(xc.x) | (f2bf(xc.y) << 16);
        xpk[kt*4+3] = f2bf(xc.z) | (f2bf(xc.w) << 16);
    }
    if (n < N) {
#pragma unroll
        for (int kt = 0; kt < 4; ++kt) {
            uint4 o = make_uint4(xpk[kt*4], xpk[kt*4+1], xpk[kt*4+2], xpk[kt*4+3]);
            *(uint4*)(xb + (size_t)n * DIM + kt * 32 + q * 8) = o;
        }
    }
    // reduce across q (lane^16, lane^32): 8 shuffles per 16 nodes total
#pragma unroll
    for (int off = 16; off < 64; off <<= 1) {
        acc.x += __shfl_xor(acc.x, off, 64);
        acc.y += __shfl_xor(acc.y, off, 64);
        acc.z += __shfl_xor(acc.z, off, 64);
        acc.w += __shfl_xor(acc.w, off, 64);
    }
    if (q == 0 && n < N) *(float4*)(xg + (size_t)n * 4) = acc;
}

// ---------------- CSR scan (2 kernels, unchanged) ----------------
__global__ __launch_bounds__(256) void scan_block_k(
    const int* __restrict__ counts, int* __restrict__ row_start,
    int* __restrict__ blocksums, int n)
{
    __shared__ int sdata[256];
    int tid = threadIdx.x;
    int base = blockIdx.x * 1024 + tid * 4;
    int v[4]; int s = 0;
#pragma unroll
    for (int j = 0; j < 4; ++j) {
        v[j] = (base + j < n) ? counts[base + j] : 0;
        s += v[j];
    }
    sdata[tid] = s;
    __syncthreads();
    for (int off = 1; off < 256; off <<= 1) {
        int t = (tid >= off) ? sdata[tid - off] : 0;
        __syncthreads();
        sdata[tid] += t;
        __syncthreads();
    }
    int run = sdata[tid] - s;
#pragma unroll
    for (int j = 0; j < 4; ++j) {
        if (base + j < n) row_start[base + j] = run;
        run += v[j];
    }
    if (tid == 255) blocksums[blockIdx.x] = sdata[255];
}

__global__ __launch_bounds__(256) void scan_add_k(
    int* __restrict__ row_start, int* __restrict__ cursor,
    const int* __restrict__ blocksums, int n, int nb)
{
    __shared__ int red[2];
    int tid = threadIdx.x;
    if (tid < 128) {
        int v = (tid < (int)blockIdx.x && tid < nb) ? blocksums[tid] : 0;
#pragma unroll
        for (int o = 1; o < 64; o <<= 1) v += __shfl_xor(v, o, 64);
        if ((tid & 63) == 0) red[tid >> 6] = v;
    }
    __syncthreads();
    int off = red[0] + red[1];

    int base = blockIdx.x * 1024 + tid * 4;
#pragma unroll
    for (int j = 0; j < 4; ++j) {
        int idx = base + j;
        if (idx < n) {
            int v = row_start[idx] + off;
            row_start[idx] = v;
            cursor[idx] = v;
        }
    }
}

// -- fused scatter + gate logit + sigmoid; payload int2 (src|t, gate) -------------
__global__ void scatter_payload_k(
    const int* __restrict__ ei, const int* __restrict__ deprel,
    const int* __restrict__ deparc, int* __restrict__ cursor,
    const float* __restrict__ xg,
    const float* __restrict__ bg_in, const float* __restrict__ bg_out,
    int2* __restrict__ pe2, int* __restrict__ rel_arr,
    const int* __restrict__ bnz, int E)
{
    int e = blockIdx.x * 256 + threadIdx.x;
    if (e >= E) return;
    int tgt = ei[E + e];
    int src = ei[e];
    int t   = deparc[e];
    int rel = deprel[e];
    int pos = atomicAdd(&cursor[tgt], 1);
    float gl = xg[(size_t)src * 4 + t];
    if (t == 0)      gl += bg_in[rel];
    else if (t == 1) gl += bg_out[rel];
    float g = 1.f / (1.f + __expf(-gl));
    pe2[pos] = make_int2(src | (t << 20), __builtin_bit_cast(int, g));
    if (*bnz != 0) rel_arr[pos] = rel;  // bias fallback only
}

// ---------------- fused aggregate(S) + GEMM(K=512) + residual + relu -------------
// Per-edge scalar-uniform fetch/consume: readlane -> SGPR, saddr gather,
// uniform scalar t-branch (one body: 2 unpack + 2 FMA). All loop bounds SGPR.
#define RFETCH(idx, PS, GS, V) do {                                                 \
    PS = __builtin_amdgcn_readlane(pgx, (idx));                                     \
    GS = __builtin_amdgcn_readlane(pgy, (idx));                                     \
    V  = xbu[((size_t)((unsigned)(PS) & 0xFFFFFu) << 6) + lane];                    \
} while (0)

#define RCONSUME(PS, GS, V) do {                                                    \
    float g_  = __builtin_bit_cast(float, (GS));                                    \
    float lo_ = __builtin_bit_cast(float, (V) << 16);                               \
    float hi_ = __builtin_bit_cast(float, (V) & 0xffff0000u);                       \
    int t_ = (int)((unsigned)(PS) >> 20);                                           \
    if (t_ == 0)      { a00 += lo_ * g_; a01 += hi_ * g_; }                         \
    else if (t_ == 1) { a10 += lo_ * g_; a11 += hi_ * g_; }                         \
    else if (t_ == 2) { a20 += lo_ * g_; a21 += hi_ * g_; }                         \
    else              { a30 += lo_ * g_; a31 += hi_ * g_; }                         \
} while (0)

__global__ __launch_bounds__(1024, 8) void fused_agg_gemm_k(
    const unsigned short* __restrict__ xb,
    const unsigned short* __restrict__ wcatT,
    const int2* __restrict__ pe2, const int* __restrict__ rel_arr,
    const int* __restrict__ row_start, const int* __restrict__ counts,
    const float* __restrict__ b_in, const float* __restrict__ b_out,
    float* __restrict__ Sb, float* __restrict__ out,
    const int* __restrict__ bnz, int N)
{
    // S-tile: 64 rows x 512 k, bf16, row stride 1024 B, XOR-swizzled. 64 KB.
    __shared__ __align__(16) unsigned char smem[64 * 1024];

    int tid  = threadIdx.x;
    int wave = tid >> 6, lane = tid & 63;     // 16 waves
    int rowb = blockIdx.x * 64;
    int bz = __builtin_amdgcn_readfirstlane((*bnz == 0) ? 1 : 0);
    const unsigned* __restrict__ xbu = (const unsigned*)xb;  // row = 64 dwords

    // ---------------- phase 1: gather-aggregate S into LDS ----------------
    // One wave per row: row = pass*16 + wave, pass 0..3. All 4 rows' metadata
    // loaded upfront; row p+1's pe chunk issued before row p's consume loop.
    int s_[4], c_[4];
#pragma unroll
    for (int p = 0; p < 4; ++p) {
        int rr = rowb + p * 16 + wave;
        int st = 0, cn = 0;
        if (rr < N) { st = row_start[rr]; cn = counts[rr]; }
        s_[p] = __builtin_amdgcn_readfirstlane(st);
        c_[p] = __builtin_amdgcn_readfirstlane(cn);
    }

    // preload chunk 0 of row (pass 0)
    int pgx = 0, pgy = 0;
    {
        int m0 = min(c_[0], 64);
        if (lane < m0) {
            int2 t0 = pe2[(size_t)s_[0] + lane];
            pgx = t0.x; pgy = t0.y;
        }
    }

#pragma unroll
    for (int p = 0; p < 4; ++p) {
        int r = p * 16 + wave;      // row in tile 0..63
        int n = rowb + r;
        bool valid = n < N;
        int start = s_[p], cnt = c_[p];

        // prefetch next row's first pe chunk (issued before consume loop)
        int nxx = 0, nxy = 0;
        if (p < 3) {
            int mn = min(c_[p + 1], 64);
            if (lane < mn) {
                int2 t1 = pe2[(size_t)s_[p + 1] + lane];
                nxx = t1.x; nxy = t1.y;
            }
        }

        float a00 = 0.f, a01 = 0.f;
        float a10 = 0.f, a11 = 0.f;
        float a20 = 0.f, a21 = 0.f;
        float a30 = 0.f, a31 = 0.f;
        float ab0 = 0.f, ab1 = 0.f;

        if (bz) {
            // fast path: depth-4 pipeline, all edge scalars in SGPRs
            for (int base2 = 0; base2 < cnt; base2 += 64) {
                if (base2) {  // chunks >0 (rare, degree>64): reload inline
                    int m2 = min(cnt - base2, 64);
                    pgx = 0; pgy = 0;
                    if (lane < m2) {
                        int2 t2 = pe2[(size_t)(start + base2) + lane];
                        pgx = t2.x; pgy = t2.y;
                    }
                }
                int m = min(cnt - base2, 64);
                int p0 = 0, p1 = 0, p2 = 0, p3 = 0;
                int q0 = 0, q1 = 0, q2 = 0, q3 = 0;
                unsigned v0 = 0, v1 = 0, v2 = 0, v3 = 0;
                if (0 < m) RFETCH(0, p0, q0, v0);
                if (1 < m) RFETCH(1, p1, q1, v1);
                if (2 < m) RFETCH(2, p2, q2, v2);
                if (3 < m) RFETCH(3, p3, q3, v3);

                for (int j = 0; j < m; j += 4) {
                    RCONSUME(p0, q0, v0);
                    if (j + 4 < m) RFETCH(j + 4, p0, q0, v0);
                    if (j + 1 < m) {
                        RCONSUME(p1, q1, v1);
                        if (j + 5 < m) RFETCH(j + 5, p1, q1, v1);
                    }
                    if (j + 2 < m) {
                        RCONSUME(p2, q2, v2);
                        if (j + 6 < m) RFETCH(j + 6, p2, q2, v2);
                    }
                    if (j + 3 < m) {
                        RCONSUME(p3, q3, v3);
                        if (j + 7 < m) RFETCH(j + 7, p3, q3, v3);
                    }
                }
            }
        } else {
            // exact generic path: also accumulate gathered bias rows (output space)
            for (int base2 = 0; base2 < cnt; base2 += 64) {
                int m = min(cnt - base2, 64);
                int lpx = 0, lpy = 0, prl = 0;
                if (lane < m) {
                    int2 pg = pe2[(size_t)(start + base2) + lane];
                    lpx = pg.x; lpy = pg.y;
                    prl = rel_arr[(size_t)(start + base2) + lane];
                }
                for (int j = 0; j < m; ++j) {
                    int ps = __builtin_amdgcn_readlane(lpx, j);
                    int gs = __builtin_amdgcn_readlane(lpy, j);
                    int rl = __builtin_amdgcn_readlane(prl, j);
                    float g_ = __builtin_bit_cast(float, gs);
                    unsigned v = xbu[((size_t)((unsigned)ps & 0xFFFFFu) << 6) + lane];
                    float lo_ = __builtin_bit_cast(float, v << 16);
                    float hi_ = __builtin_bit_cast(float, v & 0xffff0000u);
                    int t_ = (int)((unsigned)ps >> 20);
                    if (t_ == 0) {
                        a00 += lo_ * g_; a01 += hi_ * g_;
                        float2 bb = *(const float2*)(b_in + (size_t)rl * DIM + lane * 2);
                        ab0 += g_ * bb.x; ab1 += g_ * bb.y;
                    } else if (t_ == 1) {
                        a10 += lo_ * g_; a11 += hi_ * g_;
                        float2 bb = *(const float2*)(b_out + (size_t)rl * DIM + lane * 2);
                        ab0 += g_ * bb.x; ab1 += g_ * bb.y;
                    } else if (t_ == 2) { a20 += lo_ * g_; a21 += hi_ * g_; }
                    else                { a30 += lo_ * g_; a31 += hi_ * g_; }
                }
            }
        }

        if (valid) {
            // S row layout: k = t*128 + d; lane covers d=2l,2l+1 per branch.
            // swizzle: byteoff ^= (row&7)<<4 (bits 4-6; 4B alignment preserved)
            unsigned sw = (unsigned)((r & 7) << 4);
            unsigned rb = (unsigned)r * 1024;
            *(unsigned*)(&smem[rb + ((  0u + lane * 4u) ^ sw)]) = f2bf(a00) | (f2bf(a01) << 16);
            *(unsigned*)(&smem[rb + ((256u + lane * 4u) ^ sw)]) = f2bf(a10) | (f2bf(a11) << 16);
            *(unsigned*)(&smem[rb + ((512u + lane * 4u) ^ sw)]) = f2bf(a20) | (f2bf(a21) << 16);
            *(unsigned*)(&smem[rb + ((768u + lane * 4u) ^ sw)]) = f2bf(a30) | (f2bf(a31) << 16);
            if (!bz)
                *(float2*)(Sb + (size_t)n * DIM + lane * 2) = make_float2(ab0, ab1);
        }
        pgx = nxx; pgy = nxy;   // rotate prefetched pe regs
    }

    __syncthreads();

    // ---------------- phase 2: S_tile @ Wcat (K=512) ----------------
    // 16 waves: cw = wave&7 (16-col block), rw = wave>>3 (32-row half).
    // A-operand layout (proven in gemm_xv_k): col on lane&15, k = quad*8+j.
    int quad = lane >> 4, l15 = lane & 15;
    int cw = wave & 7, rw = wave >> 3;
    int colb = cw * 16 + quad * 4;
    const unsigned short* wc = wcatT + (size_t)(cw * 16 + l15) * 512;

    floatx4 ac0 = {0.f, 0.f, 0.f, 0.f}, ac1 = ac0;
    unsigned swl = (unsigned)((l15 & 7) << 4);
#pragma unroll
    for (int kt = 0; kt < 16; ++kt) {
        short8 wf = *(const short8*)(wc + kt * 32 + quad * 8);
        unsigned bo = ((unsigned)(kt * 64 + quad * 16)) ^ swl;
        short8 x0 = *(const short8*)(&smem[(unsigned)(rw * 32 +      l15) * 1024 + bo]);
        short8 x1 = *(const short8*)(&smem[(unsigned)(rw * 32 + 16 + l15) * 1024 + bo]);
        ac0 = __builtin_amdgcn_mfma_f32_16x16x32_bf16(wf, x0, ac0, 0, 0, 0);
        ac1 = __builtin_amdgcn_mfma_f32_16x16x32_bf16(wf, x1, ac1, 0, 0, 0);
    }

    // epilogue: + xb residual (+ Sb bias term if !bz), relu, store.
    // D layout (from gemm_xv_k): row = l15 (+row-group), col = colb + reg.
#define EPI(AC, RG) do {                                                            \
    int row = rowb + (RG) + l15;                                                    \
    if (row < N) {                                                                  \
        uint2 ix = *(const uint2*)(xb + (size_t)row * DIM + colb);                  \
        float4 o;                                                                   \
        o.x = (AC)[0] + bf2f(ix.x & 0xffffu);                                       \
        o.y = (AC)[1] + bf2f(ix.x >> 16);                                           \
        o.z = (AC)[2] + bf2f(ix.y & 0xffffu);                                       \
        o.w = (AC)[3] + bf2f(ix.y >> 16);                                           \
        if (!bz) {                                                                  \
            float4 sb = *(const float4*)(Sb + (size_t)row * DIM + colb);            \
            o.x += sb.x; o.y += sb.y; o.z += sb.z; o.w += sb.w;                     \
        }                                                                           \
        o.x = fmaxf(o.x, 0.f); o.y = fmaxf(o.y, 0.f);                               \
        o.z = fmaxf(o.z, 0.f); o.w = fmaxf(o.w, 0.f);                               \
        *(float4*)(out + (size_t)row * DIM + colb) = o;                             \
    }                                                                               \
} while (0)

    EPI(ac0, rw * 32);
    EPI(ac1, rw * 32 + 16);
#undef EPI
}

extern "C" void kernel_launch(void* const* d_in, const int* in_sizes, int n_in,
                              void* d_out, int out_size, void* d_ws, size_t ws_size,
                              hipStream_t stream)
{
    const float* inp    = (const float*)d_in[0];
    const int*   deprel = (const int*)d_in[1];
    const int*   deparc = (const int*)d_in[2];
    const int*   ei     = (const int*)d_in[3];
    const float* Vin    = (const float*)d_in[4];
    const float* b_in   = (const float*)d_in[5];
    const float* gin    = (const float*)d_in[6];
    const float* bg_in  = (const float*)d_in[7];
    const float* Vout   = (const float*)d_in[8];
    const float* b_out  = (const float*)d_in[9];
    const float* gout   = (const float*)d_in[10];
    const float* bg_out = (const float*)d_in[11];
    const float* Wself  = (const float*)d_in[12];
    const float* gself  = (const float*)d_in[13];
    const float* Wnorel = (const float*)d_in[14];
    const float* gnorel = (const float*)d_in[15];
    float*       out    = (float*)d_out;

    const int N = in_sizes[0] / DIM;   // 100000
    const int E = in_sizes[1];         // 400000
    const long long nbe = (long long)in_sizes[5];  // R*128

    char* ws = (char*)d_ws;
    size_t off = 0;
    auto alloc = [&](size_t bytes) -> void* {
        void* p = ws + off;
        off = (off + bytes + 255) & ~(size_t)255;
        return p;
    };
    float*          xg        = (float*)alloc((size_t)N * 4 * 4);
    int*            counts    = (int*)alloc((size_t)N * 4);   // |
    int*            bnz       = (int*)alloc(256);             // | one memset region
    int*            row_start = (int*)alloc((size_t)N * 4);
    int*            cursor    = (int*)alloc((size_t)N * 4);
    int2*           pe2       = (int2*)alloc((size_t)E * 8);
    int*            rel_arr   = (int*)alloc((size_t)E * 4);
    int*            blocksums = (int*)alloc(128 * 4);
    unsigned short* xb        = (unsigned short*)alloc((size_t)N * DIM * 2); // 25.6 MB
    unsigned short* wcatT     = (unsigned short*)alloc((size_t)128 * 512 * 2); // 128 KB
    float*          Sb        = (float*)alloc((size_t)N * DIM * 4);          // 51.2 MB

    int nb_scan  = (N + 1023) / 1024;
    int nb_edge  = (E + 255) / 256;
    int nb_node  = (N + 63) / 64;
    int nb_fused = (N + 63) / 64;

    // zero counts + bnz in one memset (adjacent in ws)
    size_t zlen = (size_t)((char*)bnz - (char*)counts) + 256;
    hipMemsetAsync(counts, 0, zlen, stream);

    conv_hist_k<<<nb_node + nb_edge + 256 + 128, 256, 0, stream>>>(
        inp, gin, gout, gself, gnorel, Vin, Vout, Wself, Wnorel,
        xb, xg, wcatT, ei, counts, b_in, b_out, bnz, nbe, N, E, nb_node, nb_edge);

    scan_block_k<<<nb_scan, 256, 0, stream>>>(counts, row_start, blocksums, N);
    scan_add_k<<<nb_scan, 256, 0, stream>>>(row_start, cursor, blocksums, N, nb_scan);
    scatter_payload_k<<<nb_edge, 256, 0, stream>>>(ei, deprel, deparc, cursor,
                                                   xg, bg_in, bg_out, pe2, rel_arr, bnz, E);

    fused_agg_gemm_k<<<nb_fused, 1024, 0, stream>>>(
        xb, wcatT, pe2, rel_arr, row_start, counts, b_in, b_out, Sb, out, bnz, N);
}